// Round 8
// baseline (389.578 us; speedup 1.0000x reference)
//
#include <hip/hip_runtime.h>
#include <hip/hip_bf16.h>

// FFB encoder, MI355X. Round 8: fused high+mid k-loop, WG=256 (one quad of 4
// waves, one 32-row h-tile each), 3 WGs/CU staggering independently. X in LDS
// (B-frag layout, single buffer, 2 light barriers/level). MidHi W wave-private
// in LDS via async global_load_lds (no barrier needed); midLo + high W stream
// from L2 with depth-1 register prefetch. Numerics identical to r5-r7.

typedef __bf16 bf16_t;
typedef __attribute__((ext_vector_type(8))) __bf16 bf16x8;
typedef __attribute__((ext_vector_type(4))) float f32x4;
typedef __attribute__((ext_vector_type(16))) float f32x16;

#define C56R 8.9126768f               // 56 / (2*pi)
#define INV7 0.14285714285714285f

// ws layout (bytes) — frag-linear, verified r4-r7
#define OFF_WMF   0        // mid W hi  [7][4mt][8kc][64lane][8bf16]
#define OFF_WMFLO 229376   // mid W lo
#define OFF_WHF   458752   // high W hi
#define OFF_EPM   688128   // [7][2hf][4mt][16r] float4 {ap0, ap1, C56R*bm, C56R*bh}

union ChunkU { bf16x8 v; unsigned int d[4]; };

__device__ __forceinline__ unsigned short bfbits(float x) {
  bf16_t b = (bf16_t)x;
  return __builtin_bit_cast(unsigned short, b);
}
__device__ __forceinline__ float bf2f(unsigned short u) {
  return __builtin_bit_cast(float, (unsigned int)u << 16);
}
__device__ __forceinline__ void pack2(float v0, float v1,
                                      unsigned int& ph, unsigned int& pl) {
  unsigned short h0 = bfbits(v0), h1 = bfbits(v1);
  ph = (unsigned int)h0 | ((unsigned int)h1 << 16);
  float l0 = v0 - bf2f(h0), l1 = v1 - bf2f(h1);
  pl = (unsigned int)bfbits(l0) | ((unsigned int)bfbits(l1) << 16);
}
// async global->LDS 16B per lane: dest = ldsbase + lane*16
__device__ __forceinline__ void stage16(const void* g, void* l) {
  __builtin_amdgcn_global_load_lds(
      (const __attribute__((address_space(1))) unsigned int*)g,
      (__attribute__((address_space(3))) unsigned int*)l, 16, 0, 0);
}

__global__ void ffb_prep(const float* __restrict__ ffnA, const float* __restrict__ sigma,
                         const float* __restrict__ Wm, const float* __restrict__ bm,
                         const float* __restrict__ Wh, const float* __restrict__ bh,
                         unsigned char* __restrict__ ws) {
  int i = blockIdx.x * 256 + threadIdx.x;  // 448*256 = 114688 exactly
  bf16_t* wmf = (bf16_t*)(ws + OFF_WMF);
  bf16_t* wml = (bf16_t*)(ws + OFF_WMFLO);
  bf16_t* whf = (bf16_t*)(ws + OFF_WHF);
  {
    // fragment reorder: [it][mt][kc][lane][j]
    int j    = i & 7;
    int lane = (i >> 3) & 63;
    int kc   = (i >> 9) & 7;
    int mt   = (i >> 12) & 3;
    int it   = i >> 14;                       // 0..6
    int ho   = (mt << 5) + (lane & 31);
    int hin  = (kc << 4) + ((lane >> 5) << 3) + j;
    int src  = (it << 14) + (ho << 7) + hin;
    float w  = Wm[src];
    bf16_t h = (bf16_t)w;
    wmf[i] = h;
    wml[i] = (bf16_t)(w - (float)h);
    whf[i] = (bf16_t)Wh[src];
  }
  if (i < 896) {
    int r  = i & 15;
    int mt = (i >> 4) & 3;
    int hf = (i >> 6) & 1;
    int it = i >> 7;                          // 0..6
    int h  = (mt << 5) + (r & 3) + ((r >> 2) << 3) + (hf << 2);
    float sg = sigma[it];
    f32x4 e;
    e.x = ffnA[it * 256 + h] * sg;
    e.y = ffnA[it * 256 + 128 + h] * sg;
    e.z = C56R * bm[it * 128 + h];
    e.w = C56R * bh[it * 128 + h];
    ((f32x4*)(ws + OFF_EPM))[i] = e;
  }
}

__launch_bounds__(256, 3)
__global__ void ffb_main(const float* __restrict__ pos,
                         const float* __restrict__ gfeat,
                         const float* __restrict__ W0,
                         const float* __restrict__ b0,
                         const unsigned char* __restrict__ ws,
                         float* __restrict__ out) {
  // [0,32K): midhi, wave-private 8KB per sub: [sub][8kc][64lane][16B]
  // [32K,48K): X hi [8kc][64lane][16B]; lo at +8192
  __shared__ __align__(16) unsigned char smem[49152];
  unsigned char* sMH = smem;
  unsigned char* sX  = smem + 32768;

  const int tid = threadIdx.x;
  const int L   = tid & 63;
  const int sub = tid >> 6;        // wave index == its mt h-tile
  const int p   = L & 31;
  const int hf  = L >> 5;
  const int n   = (blockIdx.x << 5) + p;

  const bf16_t* __restrict__ WML = (const bf16_t*)(ws + OFF_WMFLO);
  const bf16_t* __restrict__ WHF = (const bf16_t*)(ws + OFF_WHF);
  const f32x4*  __restrict__ EPM = (const f32x4*)(ws + OFF_EPM);
  const float*  __restrict__ EPW = (const float*)(ws + OFF_EPM);

  // issue level-0 midhi DMA (own tile, wave-private)
  {
    const unsigned char* src = ws + OFF_WMF + (sub << 13) + (L << 4);
    unsigned char* dst = sMH + (sub << 13);
    #pragma unroll
    for (int c = 0; c < 8; ++c) stage16(src + (c << 10), dst + (c << 10));
  }

  const float p0 = pos[n * 3 + 0], p1 = pos[n * 3 + 1], p2 = pos[n * 3 + 2];
  if (sub == 0 && hf == 0) {
    out[n * 131 + 0] = (p0 + 1.f) * 0.5f;
    out[n * 131 + 1] = (p1 + 1.f) * 0.5f;
    out[n * 131 + 2] = (p2 + 1.f) * 0.5f;
  }

  // ---- layer 0: each wave fills its 2 X chunks (B-frag layout) in LDS.
  #pragma unroll
  for (int cc = 0; cc < 2; ++cc) {
    const int c = (sub << 1) + cc;
    ChunkU chi, clo;
    #pragma unroll
    for (int jp = 0; jp < 4; ++jp) {
      int h0 = (c << 4) + (hf << 3) + 2 * jp;
      float d0 = __builtin_fmaf(p2, W0[h0*3+2], __builtin_fmaf(p1, W0[h0*3+1], p0 * W0[h0*3+0]));
      float d1 = __builtin_fmaf(p2, W0[h0*3+5], __builtin_fmaf(p1, W0[h0*3+4], p0 * W0[h0*3+3]));
      float v0 = __builtin_amdgcn_sinf(C56R * (d0 + b0[h0]));
      float v1 = __builtin_amdgcn_sinf(C56R * (d1 + b0[h0 + 1]));
      pack2(v0, v1, chi.d[jp], clo.d[jp]);
    }
    *(bf16x8*)(sX + (c << 10) + (L << 4))        = chi.v;
    *(bf16x8*)(sX + 8192 + (c << 10) + (L << 4)) = clo.v;
  }
  __syncthreads();   // X0 visible; also drains level-0 midhi DMA (vmcnt)

  f32x16 buf;
  #pragma unroll
  for (int r = 0; r < 16; ++r) buf[r] = 0.f;

  for (int it = 0; it < 8; ++it) {
    const bool doHigh = (it > 0);
    const bool doMid  = (it < 7);

    float g0 = 0.f, g1 = 0.f;
    if (doMid) {
      g0 = gfeat[n * 17 + 3 + 2 * it];
      g1 = gfeat[n * 17 + 4 + 2 * it];
    }

    // ---- fused k-loop: high(it-1) + mid(it), both read X(it) ----
    f32x16 accm, acch;
    #pragma unroll
    for (int r = 0; r < 16; ++r) { accm[r] = 0.f; acch[r] = 0.f; }
    const bf16_t* wl = WML + (it << 14) + (sub << 12) + (L << 3);
    const bf16_t* wb = WHF + ((it - 1) << 14) + (sub << 12) + (L << 3);
    const unsigned char* smh = sMH + (sub << 13) + (L << 4);
    bf16x8 fl_n, wb_n;
    if (doMid)  fl_n = *(const bf16x8*)(wl);
    if (doHigh) wb_n = *(const bf16x8*)(wb);
    #pragma unroll
    for (int kc = 0; kc < 8; ++kc) {
      bf16x8 flv = fl_n, wbv = wb_n;
      if (kc < 7) {
        if (doMid)  fl_n = *(const bf16x8*)(wl + ((kc + 1) << 9));
        if (doHigh) wb_n = *(const bf16x8*)(wb + ((kc + 1) << 9));
      }
      bf16x8 xh = *(const bf16x8*)(sX + (kc << 10) + (L << 4));
      if (doHigh)
        acch = __builtin_amdgcn_mfma_f32_32x32x16_bf16(wbv, xh, acch, 0, 0, 0);
      if (doMid) {
        bf16x8 fh = *(const bf16x8*)(smh + (kc << 10));
        bf16x8 xl = *(const bf16x8*)(sX + 8192 + (kc << 10) + (L << 4));
        accm = __builtin_amdgcn_mfma_f32_32x32x16_bf16(fh, xh, accm, 0, 0, 0);
        accm = __builtin_amdgcn_mfma_f32_32x32x16_bf16(flv, xh, accm, 0, 0, 0);
        accm = __builtin_amdgcn_mfma_f32_32x32x16_bf16(fh, xl, accm, 0, 0, 0);
      }
    }

    // ---- DMA next level's midhi (wave-private region, no barrier needed).
    // lgkm-only wait: ensure own ds_reads of midhi(it) retired before overwrite.
    if (it < 6) {
      __builtin_amdgcn_s_waitcnt(0xC07F);   // lgkmcnt(0), vmcnt/exp untouched
      const unsigned char* src = ws + OFF_WMF + ((it + 1) << 15) + (sub << 13) + (L << 4);
      unsigned char* dst = sMH + (sub << 13);
      #pragma unroll
      for (int c = 0; c < 8; ++c) stage16(src + (c << 10), dst + (c << 10));
    }

    // ---- high epilogue (regs only, cushions B1 skew) ----
    if (doHigh) {
      const int eb = ((((it - 1) << 1) + hf) << 2) + sub;
      #pragma unroll
      for (int r = 0; r < 16; ++r) {
        float cbh = EPW[(eb * 16 + r) * 4 + 3];
        buf[r] += __builtin_amdgcn_sinf(__builtin_fmaf(acch[r], C56R, cbh));
      }
    }

    // ---- mid epilogue: write X(it+1) into B-layout LDS ----
    if (doMid) {
      __syncthreads();   // B1: all 4 waves done reading X(it)
      const int eb = (((it << 1) + hf) << 2) + sub;
      #pragma unroll
      for (int rp = 0; rp < 8; ++rp) {
        const int r = 2 * rp;
        f32x4 e0 = EPM[eb * 16 + r];
        f32x4 e1 = EPM[eb * 16 + r + 1];
        float sg0 = __builtin_amdgcn_sinf(__builtin_amdgcn_fractf(__builtin_fmaf(g1, e0.y, g0 * e0.x)));
        float sg1 = __builtin_amdgcn_sinf(__builtin_amdgcn_fractf(__builtin_fmaf(g1, e1.y, g0 * e1.x)));
        float sm0 = __builtin_amdgcn_sinf(__builtin_fmaf(accm[r],     C56R, e0.z));
        float sm1 = __builtin_amdgcn_sinf(__builtin_fmaf(accm[r + 1], C56R, e1.z));
        unsigned int phv, plv;
        pack2(sg0 + sm0, sg1 + sm1, phv, plv);
        const int h   = (sub << 5) + (r & 3) + ((r >> 2) << 3) + (hf << 2);
        const int off = ((h >> 4) << 10) + ((p + (((h >> 3) & 1) << 5)) << 4) + ((h & 7) << 1);
        *(unsigned int*)(sX + off)        = phv;
        *(unsigned int*)(sX + 8192 + off) = plv;
      }
      __syncthreads();   // B2: X(it+1) visible (also drains own DMA vmcnt)
    }
  }

  // ---- final store: this wave's mt=sub rows for its 32 points.
  float* op = out + (size_t)n * 131 + 3;
  #pragma unroll
  for (int r = 0; r < 16; ++r) {
    const int h = (sub << 5) + (r & 3) + ((r >> 2) << 3) + (hf << 2);
    op[h] = buf[r] * INV7;
  }
}

extern "C" void kernel_launch(void* const* d_in, const int* in_sizes, int n_in,
                              void* d_out, int out_size, void* d_ws, size_t ws_size,
                              hipStream_t stream) {
  (void)in_sizes; (void)n_in; (void)out_size; (void)ws_size;
  const float* pos   = (const float*)d_in[0];
  const float* gfeat = (const float*)d_in[1];
  const float* ffnA  = (const float*)d_in[2];
  const float* sigma = (const float*)d_in[3];
  const float* W0    = (const float*)d_in[4];
  const float* b0    = (const float*)d_in[5];
  const float* Wm    = (const float*)d_in[6];
  const float* bm    = (const float*)d_in[7];
  const float* Wh    = (const float*)d_in[8];
  const float* bh    = (const float*)d_in[9];
  float* out = (float*)d_out;
  unsigned char* ws = (unsigned char*)d_ws;

  hipLaunchKernelGGL(ffb_prep, dim3(448), dim3(256), 0, stream,
                     ffnA, sigma, Wm, bm, Wh, bh, ws);
  hipLaunchKernelGGL(ffb_main, dim3(4096), dim3(256), 0, stream,
                     pos, gfeat, W0, b0, ws, out);
}